// Round 2
// baseline (343.208 us; speedup 1.0000x reference)
//
#include <hip/hip_runtime.h>

// SPU(z) = z^2 - 0.5           for z >= 0
//        = sigmoid(-z) - 1     for z <  0
//
// sigmoid(-z) - 1 = 1/(1+e^z) - 1   (cancellation-free; == -e^z/(1+e^z))
//
// Fast-math forms (tolerance is loose — harness passes at absmax 0.03125):
//   __expf                -> native v_exp_f32 (vs ~10-op __ocml_exp_f32)
//   __builtin_amdgcn_rcpf -> v_rcp_f32 (vs ~10-op correctly-rounded div chain)
// Edge behavior: z >> 0 -> e = inf -> rcp(inf)=0 -> neg=-1 (unused, select takes pos).
//                z << 0 -> e = 0   -> rcp(1)=1  -> neg= 0 (correct limit).

typedef float v4f __attribute__((ext_vector_type(4)));

__device__ __forceinline__ float spu_fast(float z) {
    float e   = __expf(z);                               // v_exp_f32 path
    float neg = __builtin_amdgcn_rcpf(1.0f + e) - 1.0f;  // == -e/(1+e)
    float pos = fmaf(z, z, -0.5f);
    return (z >= 0.0f) ? pos : neg;
}

__global__ __launch_bounds__(256)
void spu_box_kernel(const float* __restrict__ x,
                    const float* __restrict__ l_in,
                    const float* __restrict__ u_in,
                    float* __restrict__ x_out,
                    float* __restrict__ l_out,
                    float* __restrict__ u_out,
                    int n4)                  // number of float4 groups
{
    int i = blockIdx.x * blockDim.x + threadIdx.x;
    if (i >= n4) return;

    v4f xv = ((const v4f*)x)[i];
    v4f lv = ((const v4f*)l_in)[i];
    v4f uv = ((const v4f*)u_in)[i];

    v4f xo, lo, uo;

    #pragma unroll
    for (int k = 0; k < 4; ++k) {
        float xs = xv[k];
        float ls = lv[k];
        float us = uv[k];

        float sx = spu_fast(xs);
        float sl = spu_fast(ls);
        float su = spu_fast(us);

        // l_out: l>=0 -> spu(l); else u<=0 -> spu(u); else -0.5
        lo[k] = (ls >= 0.0f) ? sl : ((us <= 0.0f) ? su : -0.5f);
        // u_out: u<=0 -> spu(l); else spu(u)
        uo[k] = (us <= 0.0f) ? sl : su;
        xo[k] = sx;
    }

    // Streaming outputs: written once, never re-read -> nt stores (skip L2 alloc).
    __builtin_nontemporal_store(xo, (v4f*)x_out + i);
    __builtin_nontemporal_store(lo, (v4f*)l_out + i);
    __builtin_nontemporal_store(uo, (v4f*)u_out + i);
}

// Scalar tail (n not divisible by 4) — not hit for DIM=16777216 but kept safe.
__global__ void spu_box_tail(const float* __restrict__ x,
                             const float* __restrict__ l_in,
                             const float* __restrict__ u_in,
                             float* __restrict__ x_out,
                             float* __restrict__ l_out,
                             float* __restrict__ u_out,
                             int start, int n)
{
    int i = start + blockIdx.x * blockDim.x + threadIdx.x;
    if (i >= n) return;
    float xs = x[i], ls = l_in[i], us = u_in[i];
    float sx = spu_fast(xs), sl = spu_fast(ls), su = spu_fast(us);
    x_out[i] = sx;
    l_out[i] = (ls >= 0.0f) ? sl : ((us <= 0.0f) ? su : -0.5f);
    u_out[i] = (us <= 0.0f) ? sl : su;
}

extern "C" void kernel_launch(void* const* d_in, const int* in_sizes, int n_in,
                              void* d_out, int out_size, void* d_ws, size_t ws_size,
                              hipStream_t stream) {
    const float* x    = (const float*)d_in[0];
    const float* l_in = (const float*)d_in[1];
    const float* u_in = (const float*)d_in[2];

    const int n = in_sizes[0];           // 16777216
    float* out   = (float*)d_out;        // [x_out | l_out | u_out], each n floats
    float* x_out = out;
    float* l_out = out + n;
    float* u_out = out + 2 * (size_t)n;

    const int n4 = n / 4;
    const int block = 256;
    const int grid = (n4 + block - 1) / block;
    spu_box_kernel<<<grid, block, 0, stream>>>(x, l_in, u_in, x_out, l_out, u_out, n4);

    const int tail_start = n4 * 4;
    if (tail_start < n) {
        const int tail = n - tail_start;
        spu_box_tail<<<(tail + 63) / 64, 64, 0, stream>>>(x, l_in, u_in,
                                                          x_out, l_out, u_out,
                                                          tail_start, n);
    }
}

// Round 3
// 334.349 us; speedup vs baseline: 1.0265x; 1.0265x over previous
//
#include <hip/hip_runtime.h>

// SPU(z) = z^2 - 0.5           for z >= 0
//        = sigmoid(-z) - 1     for z <  0
// sigmoid(-z) - 1 = 1/(1+e^z) - 1   (cancellation-free; == -e^z/(1+e^z))
//
// Structure notes (Round 2 post-mortem):
//  - one-shot 16384-block version was latency-bound: 121 µs @ 2.5 TB/s,
//    VALUBusy 11% — one load phase per thread, no MLP.
//  - now: 2048 blocks x 256 threads grid-stride (8 blocks/CU = 32 waves/CU),
//    2 independent float4 batches in flight per iteration (6 loads issued
//    before any compute) — per-wave memory-level parallelism hides HBM latency.
//  - plain stores (fill kernel hits 6.6 TB/s with them; nt was neutral).

typedef float v4f __attribute__((ext_vector_type(4)));

__device__ __forceinline__ float spu_fast(float z) {
    float e   = __expf(z);                               // v_exp_f32 path
    float neg = __builtin_amdgcn_rcpf(1.0f + e) - 1.0f;  // == -e/(1+e)
    float pos = fmaf(z, z, -0.5f);
    return (z >= 0.0f) ? pos : neg;
}

__device__ __forceinline__ void spu_box_v4(v4f xv, v4f lv, v4f uv,
                                           v4f& xo, v4f& lo, v4f& uo) {
    #pragma unroll
    for (int k = 0; k < 4; ++k) {
        float xs = xv[k], ls = lv[k], us = uv[k];
        float sx = spu_fast(xs);
        float sl = spu_fast(ls);
        float su = spu_fast(us);
        // l_out: l>=0 -> spu(l); else u<=0 -> spu(u); else -0.5
        lo[k] = (ls >= 0.0f) ? sl : ((us <= 0.0f) ? su : -0.5f);
        // u_out: u<=0 -> spu(l); else spu(u)
        uo[k] = (us <= 0.0f) ? sl : su;
        xo[k] = sx;
    }
}

__global__ __launch_bounds__(256)
void spu_box_kernel(const v4f* __restrict__ x4,
                    const v4f* __restrict__ l4,
                    const v4f* __restrict__ u4,
                    v4f* __restrict__ xo4,
                    v4f* __restrict__ lo4,
                    v4f* __restrict__ uo4,
                    int n4)                  // number of float4 groups
{
    const int stride = gridDim.x * blockDim.x;
    int i0 = blockIdx.x * blockDim.x + threadIdx.x;

    // Two independent batches per iteration: all 6 loads issue before any
    // compute/store, so each wave keeps >=6 global loads in flight.
    for (; i0 + stride < n4; i0 += 2 * stride) {
        const int i1 = i0 + stride;
        v4f xa = x4[i0], la = l4[i0], ua = u4[i0];
        v4f xb = x4[i1], lb = l4[i1], ub = u4[i1];

        v4f xoa, loa, uoa, xob, lob, uob;
        spu_box_v4(xa, la, ua, xoa, loa, uoa);
        spu_box_v4(xb, lb, ub, xob, lob, uob);

        xo4[i0] = xoa; lo4[i0] = loa; uo4[i0] = uoa;
        xo4[i1] = xob; lo4[i1] = lob; uo4[i1] = uob;
    }
    if (i0 < n4) {                           // odd leftover batch
        v4f xa = x4[i0], la = l4[i0], ua = u4[i0];
        v4f xoa, loa, uoa;
        spu_box_v4(xa, la, ua, xoa, loa, uoa);
        xo4[i0] = xoa; lo4[i0] = loa; uo4[i0] = uoa;
    }
}

// Scalar tail (n not divisible by 4) — not hit for DIM=16777216 but kept safe.
__global__ void spu_box_tail(const float* __restrict__ x,
                             const float* __restrict__ l_in,
                             const float* __restrict__ u_in,
                             float* __restrict__ x_out,
                             float* __restrict__ l_out,
                             float* __restrict__ u_out,
                             int start, int n)
{
    int i = start + blockIdx.x * blockDim.x + threadIdx.x;
    if (i >= n) return;
    float xs = x[i], ls = l_in[i], us = u_in[i];
    float sx = spu_fast(xs), sl = spu_fast(ls), su = spu_fast(us);
    x_out[i] = sx;
    l_out[i] = (ls >= 0.0f) ? sl : ((us <= 0.0f) ? su : -0.5f);
    u_out[i] = (us <= 0.0f) ? sl : su;
}

extern "C" void kernel_launch(void* const* d_in, const int* in_sizes, int n_in,
                              void* d_out, int out_size, void* d_ws, size_t ws_size,
                              hipStream_t stream) {
    const float* x    = (const float*)d_in[0];
    const float* l_in = (const float*)d_in[1];
    const float* u_in = (const float*)d_in[2];

    const int n = in_sizes[0];           // 16777216
    float* out   = (float*)d_out;        // [x_out | l_out | u_out], each n floats
    float* x_out = out;
    float* l_out = out + n;
    float* u_out = out + 2 * (size_t)n;

    const int n4 = n / 4;
    const int block = 256;
    int grid = (n4 + block - 1) / block;
    if (grid > 2048) grid = 2048;        // 8 blocks/CU, grid-stride the rest

    spu_box_kernel<<<grid, block, 0, stream>>>(
        (const v4f*)x, (const v4f*)l_in, (const v4f*)u_in,
        (v4f*)x_out, (v4f*)l_out, (v4f*)u_out, n4);

    const int tail_start = n4 * 4;
    if (tail_start < n) {
        const int tail = n - tail_start;
        spu_box_tail<<<(tail + 63) / 64, 64, 0, stream>>>(x, l_in, u_in,
                                                          x_out, l_out, u_out,
                                                          tail_start, n);
    }
}